// Round 9
// baseline (15.204 us; speedup 1.0000x reference)
//
#include <hip/hip_runtime.h>

#define N 4096
#define BLOCK 512             // 8 waves/block, one particle i per wave
#define NB (N / 8)            // 512 blocks, 2 per CU (LDS-capped at 3)
#define NSTEP (N / 64)        // 64 j-steps per wave (one j per lane per step)

// Single-dispatch kernel:
//  - stage all of q (48 KB) into LDS
//  - wave w computes full force on particle i = blockIdx.x*8 + w:
//    fully-unrolled 64 steps; all ds_reads use one base (lane*12) plus
//    compile-time immediate offsets (st*768 + {0,4,8} < 64 KB) -> zero
//    address arithmetic in the loop
//  - 6-step shfl_xor butterfly reduces (fx,fy,fz); lane 0 stores dp[i]
//  - dq = p/m folded in (24 elements per block, loads issued pre-barrier)
__global__ __launch_bounds__(BLOCK, 4)
void lj_single_kernel(const float* __restrict__ q, const float* __restrict__ p,
                      const float* __restrict__ m, float* __restrict__ out) {
    __shared__ float qs[N * 3];          // 48 KB
    const int tid  = threadIdx.x;
    const int lane = tid & 63;
    const int wave = tid >> 6;           // 0..7
    const int i    = blockIdx.x * 8 + wave;

    // own particle position: wave-uniform -> scalar loads
    const float qx = q[i * 3 + 0];
    const float qy = q[i * 3 + 1];
    const float qz = q[i * 3 + 2];

    // dq tail inputs: issue global loads early, overlap with staging
    const int dq_n = (N * 3) / NB;       // 24
    float pv = 0.f, mv = 1.f;
    int u = 0;
    if (tid < dq_n) {
        u  = blockIdx.x * dq_n + tid;
        pv = p[u];
        mv = m[u / 3];
    }

    // stage q into LDS, float4-coalesced: 3072 float4 / 512 threads = 6 each
    {
        const float4* __restrict__ q4 = (const float4*)q;
        float4* __restrict__ qs4 = (float4*)qs;
        #pragma unroll
        for (int k = 0; k < (N * 3) / 4 / BLOCK; ++k)
            qs4[k * BLOCK + tid] = q4[k * BLOCK + tid];
    }
    __syncthreads();

    float fx = 0.f, fy = 0.f, fz = 0.f;
    const int sdiag = i >> 6;            // the step whose j-window contains i
    const float* __restrict__ qsl = qs + lane * 3;   // single base register

    #pragma unroll                        // FULL unroll: imm-offset ds_reads
    for (int st = 0; st < NSTEP; ++st) {
        const float dx = qx - qsl[st * 192 + 0];     // offset: st*768+0
        const float dy = qy - qsl[st * 192 + 1];     // offset: st*768+4
        const float dz = qz - qsl[st * 192 + 2];     // offset: st*768+8
        const float r2 = fmaf(dx, dx, fmaf(dy, dy, dz * dz));
        const float u1 = __builtin_amdgcn_rcpf(r2);  // r^-2  (v_rcp_f32)
        const float u2 = u1 * u1;                    // r^-4
        const float u3 = u2 * u1;                    // r^-6
        const float u4 = u2 * u2;                    // r^-8
        float s = u4 * fmaf(-48.0f, u3, 24.0f);      // 24 r^-8 - 48 r^-14
        if (st == sdiag)                 // wave-uniform, 1 of 64 steps
            s = (st * 64 + lane == i) ? 0.0f : s;
        fx = fmaf(s, dx, fx);
        fy = fmaf(s, dy, fy);
        fz = fmaf(s, dz, fz);
    }

    // in-register wave reduction (fixed order -> deterministic)
    #pragma unroll
    for (int off = 32; off > 0; off >>= 1) {
        fx += __shfl_xor(fx, off, 64);
        fy += __shfl_xor(fy, off, 64);
        fz += __shfl_xor(fz, off, 64);
    }
    if (lane == 0) {
        out[N * 3 + i * 3 + 0] = fx;
        out[N * 3 + i * 3 + 1] = fy;
        out[N * 3 + i * 3 + 2] = fz;
    }

    // dq = p / m (loads already in flight)
    if (tid < dq_n)
        out[u] = pv / mv;
}

extern "C" void kernel_launch(void* const* d_in, const int* in_sizes, int n_in,
                              void* d_out, int out_size, void* d_ws, size_t ws_size,
                              hipStream_t stream) {
    const float* q = (const float*)d_in[0];
    const float* p = (const float*)d_in[1];
    const float* m = (const float*)d_in[2];
    float* out = (float*)d_out;

    lj_single_kernel<<<NB, BLOCK, 0, stream>>>(q, p, m, out);
}